// Round 1
// baseline (283.899 us; speedup 1.0000x reference)
//
#include <hip/hip_runtime.h>
#include <math.h>

// TwoBranchDH_SFNN: B=128, T=2048, H=512, D_IN=40, D_OUT=1
//
// R12: FIR collapse. D_OUT==1 => the network is linear up to the output
// sigmoid. out[b,t] = sigmoid( sum_{s<L,d} g[s,d]*x[b,t-s,d] + c(t) ) with
//   g[s,d] = sum_h Wo[h]*K_h(s)*W[h,d],
//   K_h(s) = (1-a)(1-b)(a^{s+1}-b^{s+1})/(a-b)   (a=sig(tau_m), b=sig(tau_n))
//   c(t)   = exact zero-state bias response (closed form) + bo.
// L=192 truncation strictly dominates the previous kernel's 128-step
// warm-start accuracy, and everything stays f32 (no bf16 anywhere).
//
// prep1/prep2 build g (stored transposed [d][192] for uniform s_loads) and c.
// fir_main: 512 blocks = 128 b x 4 t-tiles(512). 512 thr = 64 i x 8 sh:
// thread owns outputs [8i,8i+8) and lag slice [24sh,24sh+24). x window
// [20 d][704 t] f32 in LDS (row stride 708), per d-row: 8x ds_read_b128
// (lanes stride 32B -> conflict-free) + 192 v_fmac with SGPR g operand.
// Two d-phases (d<20 / d>=20) reuse the same 56.6KB window -> 2 blocks/CU.

#define B_   128
#define T_   2048
#define H_   512
#define DIN  40
#define L_   192
#define GSD  (L_ * DIN)      // 7680
#define TT   704             // 512 + L_
#define RS   708             // padded LDS row stride (f32)

// static device workspace (avoids d_ws assumptions / host API calls)
__device__ float d_gpart[16 * GSD];
__device__ float d_cpart[16 * T_];
__device__ float d_gT[DIN * L_];     // [d][s]
__device__ float d_c[T_];            // bias transient + bo

__device__ __forceinline__ float sigmf(float v) { return 1.f / (1.f + __expf(-v)); }

// ---------------- prep1: partial sums over 32-h chunks ----------------
__global__ void prep1(const float* __restrict__ W1, const float* __restrict__ b1v,
                      const float* __restrict__ W2, const float* __restrict__ b2v,
                      const float* __restrict__ Wo, const float* __restrict__ tau_m,
                      const float* __restrict__ tau_n1, const float* __restrict__ tau_n2)
{
    int gid = blockIdx.x * 256 + threadIdx.x;
    if (gid < 16 * GSD) {
        const int chunk = gid & 15;
        const int p = gid >> 4;              // p = s*DIN + d
        const int s = p / DIN;
        const int d = p - s * DIN;
        const float fs1 = (float)(s + 1);
        float acc = 0.f;
        for (int hh = 0; hh < 32; ++hh) {
            const int h = chunk * 32 + hh;
            const float a = sigmf(tau_m[h]);
            float b = (d < 20) ? sigmf(tau_n1[h]) : sigmf(tau_n2[h]);
            const float w = (d < 20) ? W1[h * 20 + d] : W2[h * 20 + d - 20];
            float diff = a - b;
            if (fabsf(diff) < 1e-5f) { b = a - 1e-5f; diff = 1e-5f; }
            const float ap = exp2f(fs1 * log2f(a));
            const float bp = exp2f(fs1 * log2f(b));
            const float K = (1.f - a) * (1.f - b) * (ap - bp) / diff;
            acc += Wo[h] * K * w;
        }
        d_gpart[chunk * GSD + p] = acc;
    } else {
        int g2 = gid - 16 * GSD;             // < 16*T_
        const int chunk = g2 & 15;
        const int t = g2 >> 4;
        const float ft1 = (float)(t + 1);
        float acc = 0.f;
        for (int hh = 0; hh < 32; ++hh) {
            const int h = chunk * 32 + hh;
            const float a = sigmf(tau_m[h]);
            const float ap = exp2f(ft1 * log2f(a));
            float acc_h = 0.f;
            {
                float bb = sigmf(tau_n1[h]);
                float diff = a - bb;
                if (fabsf(diff) < 1e-5f) { bb = a - 1e-5f; diff = 1e-5f; }
                const float bp = exp2f(ft1 * log2f(bb));
                acc_h += b1v[h] * (a * (1.f - bb) * (1.f - ap)
                                 - bb * (1.f - a) * (1.f - bp)) / diff;
            }
            {
                float bb = sigmf(tau_n2[h]);
                float diff = a - bb;
                if (fabsf(diff) < 1e-5f) { bb = a - 1e-5f; diff = 1e-5f; }
                const float bp = exp2f(ft1 * log2f(bb));
                acc_h += b2v[h] * (a * (1.f - bb) * (1.f - ap)
                                 - bb * (1.f - a) * (1.f - bp)) / diff;
            }
            acc += Wo[h] * acc_h;
        }
        d_cpart[chunk * T_ + t] = acc;
    }
}

// ---------------- prep2: finalize g (transposed) and c ----------------
__global__ void prep2(const float* __restrict__ bo)
{
    int gid = blockIdx.x * 256 + threadIdx.x;
    if (gid < GSD) {
        const int d = gid / L_;
        const int s = gid - d * L_;
        const int p = s * DIN + d;
        float acc = 0.f;
#pragma unroll
        for (int k = 0; k < 16; ++k) acc += d_gpart[k * GSD + p];
        d_gT[gid] = acc;                     // d_gT[d*L_ + s]
    } else if (gid < GSD + T_) {
        const int t = gid - GSD;
        float acc = bo[0];
#pragma unroll
        for (int k = 0; k < 16; ++k) acc += d_cpart[k * T_ + t];
        d_c[t] = acc;
    }
}

// ---------------- main FIR kernel ----------------
__global__ __launch_bounds__(512, 4) void fir_main(const float* __restrict__ x,
                                                   float* __restrict__ out)
{
    __shared__ __align__(16) float xw[20 * RS];   // 56640 B

    const int blk = blockIdx.x;
    const int b   = blk >> 2;
    const int t0  = (blk & 3) << 9;               // tile * 512
    const int tid = threadIdx.x;
    const int i   = tid & 63;                      // output group
    const int sh  = tid >> 6;                      // lag slice == wave id
    const int sh_u = __builtin_amdgcn_readfirstlane(sh);

    const float* __restrict__ xb = x + (size_t)b * (T_ * DIN);

    float y[8];
#pragma unroll
    for (int r = 0; r < 8; ++r) y[r] = 0.f;

    // window base for this thread's reads: tt = A0 + (24 + r - j)
    const int A0 = 8 * i + 168 - 24 * sh;          // always >=0, 16B aligned

    for (int dh = 0; dh < 2; ++dh) {
        __syncthreads();   // previous-phase readers done before overwrite
        // stage x[t0-192 .. t0+512) x d in [20dh,20dh+20) -> xw[dl][tt]
        for (int k = 0; k < 7; ++k) {
            const int phi = tid + 512 * k;
            if (phi < TT * 5) {
                const int tr = phi / 5;
                const int dq = phi - tr * 5;
                const int tg = t0 - L_ + tr;
                float4 v = make_float4(0.f, 0.f, 0.f, 0.f);
                if (tg >= 0)
                    v = *(const float4*)&xb[tg * DIN + dh * 20 + dq * 4];
                float* col = &xw[(dq * 4) * RS + tr];
                col[0]      = v.x;
                col[RS]     = v.y;
                col[2 * RS] = v.z;
                col[3 * RS] = v.w;
            }
        }
        __syncthreads();

        for (int dl = 0; dl < 20; ++dl) {
            const float* __restrict__ rowp = &xw[dl * RS];
            const float* __restrict__ gr = &d_gT[(dh * 20 + dl) * L_ + 24 * sh_u];
            float W[32];
#pragma unroll
            for (int q = 0; q < 8; ++q)
                *(float4*)&W[4 * q] = *(const float4*)&rowp[A0 + 4 * q];
#pragma unroll
            for (int j = 0; j < 24; ++j) {
                const float gj = gr[j];        // wave-uniform -> s_load/SGPR
#pragma unroll
                for (int r = 0; r < 8; ++r)
                    y[r] = fmaf(gj, W[24 + r - j], y[r]);
            }
        }
    }

    // reduce the 8 lag-slice partials per output
    __syncthreads();
    if (sh > 0) {
        float* p = &xw[((sh - 1) * 64 + i) * 12];  // stride 12: aligned, spread
        *(float4*)&p[0] = make_float4(y[0], y[1], y[2], y[3]);
        *(float4*)&p[4] = make_float4(y[4], y[5], y[6], y[7]);
    }
    __syncthreads();
    if (sh == 0) {
        for (int pw = 0; pw < 7; ++pw) {
            const float* p = &xw[(pw * 64 + i) * 12];
            float4 u0 = *(const float4*)&p[0];
            float4 u1 = *(const float4*)&p[4];
            y[0] += u0.x; y[1] += u0.y; y[2] += u0.z; y[3] += u0.w;
            y[4] += u1.x; y[5] += u1.y; y[6] += u1.z; y[7] += u1.w;
        }
        const float4 c0 = *(const float4*)&d_c[t0 + 8 * i];
        const float4 c1 = *(const float4*)&d_c[t0 + 8 * i + 4];
        float4 o0, o1;
        o0.x = sigmf(y[0] + c0.x); o0.y = sigmf(y[1] + c0.y);
        o0.z = sigmf(y[2] + c0.z); o0.w = sigmf(y[3] + c0.w);
        o1.x = sigmf(y[4] + c1.x); o1.y = sigmf(y[5] + c1.y);
        o1.z = sigmf(y[6] + c1.z); o1.w = sigmf(y[7] + c1.w);
        float* op = out + (size_t)b * T_ + t0 + 8 * i;
        *(float4*)&op[0] = o0;
        *(float4*)&op[4] = o1;
    }
}

extern "C" void kernel_launch(void* const* d_in, const int* in_sizes, int n_in,
                              void* d_out, int out_size, void* d_ws, size_t ws_size,
                              hipStream_t stream)
{
    const float* x      = (const float*)d_in[0];
    const float* W1     = (const float*)d_in[1];
    const float* b1     = (const float*)d_in[2];
    const float* W2     = (const float*)d_in[3];
    const float* b2     = (const float*)d_in[4];
    const float* Wo     = (const float*)d_in[5];
    const float* bo     = (const float*)d_in[6];
    const float* tau_m  = (const float*)d_in[7];
    const float* tau_n1 = (const float*)d_in[8];
    const float* tau_n2 = (const float*)d_in[9];

    // (16*7680 + 16*2048) / 256 = 608 exactly; (7680 + 2048) / 256 = 38 exactly
    hipLaunchKernelGGL(prep1, dim3(608), dim3(256), 0, stream,
                       W1, b1, W2, b2, Wo, tau_m, tau_n1, tau_n2);
    hipLaunchKernelGGL(prep2, dim3(38), dim3(256), 0, stream, bo);
    hipLaunchKernelGGL(fir_main, dim3(512), dim3(512), 0, stream,
                       x, (float*)d_out);
}

// Round 2
// 262.102 us; speedup vs baseline: 1.0832x; 1.0832x over previous
//
#include <hip/hip_runtime.h>
#include <math.h>

// TwoBranchDH_SFNN: B=128, T=2048, H=512, D_IN=40, D_OUT=1
//
// R13 = R12's FIR collapse with the two measured problems fixed:
//  1) fir_main was LDS-bank-conflict-bound (6.6e7 conflict cycles ~= 70% of
//     runtime): per-lane window stride was 32B (16-way bank aliasing).
//     New mapping: thread = (lg: 48-lag slice x 4) x (og: 4 outputs x 128).
//     Lanes are consecutive og -> ds_read_b128 per-lane stride 16B ->
//     contiguous 1KB per instruction, conflict-free floor.
//  2) prep1 cost ~130us (transcendentals + scattered loads recomputed
//     per (element x 32h)). Now: prepA writes P1/P2 [192s x 512h] with
//     one closed-form element per thread (coalesced h-fast layout) and
//     computes c(t) with 32 t-parallel blocks; prepB does g = P*W as a
//     120-block split-h reduction. Same math as R12 (verified).
//
// out[b,t] = sigmoid( sum_{s<192,d} g[s,d]*x[b,t-s,d] + c(t) ), f32 only.

#define B_   128
#define T_   2048
#define DIN  40
#define L_   192
#define TT   704             // 512 + 192 staged t-window
#define RS   708             // LDS row stride (floats)

// static device workspace
__device__ float d_P1[L_ * 512];     // [s][h]  branch 1 (d<20)
__device__ float d_P2[L_ * 512];     // [s][h]  branch 2 (d>=20)
__device__ float d_gT[DIN * L_];     // [d][s]
__device__ float d_c[T_];            // bias transient + bo

__device__ __forceinline__ float sigmf(float v) { return 1.f / (1.f + __expf(-v)); }

// ---------------- prepA: P elements (blocks 0..767) + c(t) (768..799) ----
__global__ __launch_bounds__(256) void prepA(
    const float* __restrict__ Wo, const float* __restrict__ tau_m,
    const float* __restrict__ tau_n1, const float* __restrict__ tau_n2,
    const float* __restrict__ b1v, const float* __restrict__ b2v,
    const float* __restrict__ bo)
{
    __shared__ float cb[4][64];
    const int blk = blockIdx.x, tid = threadIdx.x;
    if (blk < 768) {
        const int eid = blk * 256 + tid;          // [0, 2*192*512)
        const int br  = (eid >= L_ * 512) ? 1 : 0;
        const int p   = eid - br * (L_ * 512);
        const int s   = p >> 9, h = p & 511;      // h fast -> coalesced
        const float a = sigmf(tau_m[h]);
        float b = sigmf(br ? tau_n2[h] : tau_n1[h]);
        float diff = a - b;
        if (fabsf(diff) < 1e-5f) { b = a - 1e-5f; diff = 1e-5f; }
        const float fs1 = (float)(s + 1);
        const float ap = exp2f(fs1 * log2f(a));
        const float bp = exp2f(fs1 * log2f(b));
        const float K = (1.f - a) * (1.f - b) * (ap - bp) / diff;
        (br ? d_P2 : d_P1)[s * 512 + h] = Wo[h] * K;
    } else {
        const int cblk = blk - 768;               // 0..31 -> 64 t each
        const int tl = tid & 63;
        const int hc = tid >> 6;                  // 4 h-chunks of 128
        const int t  = cblk * 64 + tl;
        const float ft1 = (float)(t + 1);
        float acc = 0.f;
        for (int hh = 0; hh < 128; ++hh) {
            const int h = hc * 128 + hh;
            const float a  = sigmf(tau_m[h]);
            const float ap = exp2f(ft1 * log2f(a));
            float acc_h = 0.f;
            {
                float bb = sigmf(tau_n1[h]);
                float diff = a - bb;
                if (fabsf(diff) < 1e-5f) { bb = a - 1e-5f; diff = 1e-5f; }
                const float bp = exp2f(ft1 * log2f(bb));
                acc_h += b1v[h] * (a * (1.f - bb) * (1.f - ap)
                                 - bb * (1.f - a) * (1.f - bp)) / diff;
            }
            {
                float bb = sigmf(tau_n2[h]);
                float diff = a - bb;
                if (fabsf(diff) < 1e-5f) { bb = a - 1e-5f; diff = 1e-5f; }
                const float bp = exp2f(ft1 * log2f(bb));
                acc_h += b2v[h] * (a * (1.f - bb) * (1.f - ap)
                                 - bb * (1.f - a) * (1.f - bp)) / diff;
            }
            acc += Wo[h] * acc_h;
        }
        cb[hc][tl] = acc;
        __syncthreads();
        if (tid < 64)
            d_c[cblk * 64 + tid] = cb[0][tid] + cb[1][tid] + cb[2][tid]
                                 + cb[3][tid] + bo[0];
    }
}

// ---------------- prepB: g[d][s] = sum_h P_br[s,h] * W_br[h, d%20] --------
__global__ __launch_bounds__(256) void prepB(
    const float* __restrict__ W1, const float* __restrict__ W2)
{
    __shared__ float pb[4][64];
    const int tid = threadIdx.x;
    const int o  = tid & 63;
    const int hc = tid >> 6;                      // 4 h-chunks of 128
    const int gid = blockIdx.x * 64 + o;          // [0, 7680)
    const int s = gid / 40, d = gid - s * 40;
    const float* __restrict__ P = (d < 20) ? d_P1 : d_P2;
    const float* __restrict__ W = (d < 20) ? W1 : W2;
    const int dm = (d < 20) ? d : d - 20;
    float acc = 0.f;
    for (int hh = 0; hh < 128; ++hh) {
        const int h = hc * 128 + hh;
        acc += P[s * 512 + h] * W[h * 20 + dm];   // P broadcast, W coalesced
    }
    pb[hc][o] = acc;
    __syncthreads();
    if (tid < 64) {
        const int g2 = blockIdx.x * 64 + tid;
        const int s2 = g2 / 40, d2 = g2 - s2 * 40;
        d_gT[d2 * L_ + s2] = pb[0][tid] + pb[1][tid] + pb[2][tid] + pb[3][tid];
    }
}

// ---------------- main FIR kernel ----------------
// 512 blocks = 128 b x 4 t-tiles(512). 512 thr = 4 lg x 128 og.
// thread: outputs t0+4*og+{0..3}, lags [48*lg, 48*lg+48).
// Window reads: 13x ds_read_b128, per-lane stride 16B (conflict-free).
__global__ __launch_bounds__(512, 4) void fir_main(const float* __restrict__ x,
                                                   float* __restrict__ out)
{
    __shared__ __align__(16) float xw[20 * RS];   // 56640 B -> 2 blocks/CU

    const int blk = blockIdx.x;
    const int b   = blk >> 2;
    const int t0  = (blk & 3) << 9;
    const int tid = threadIdx.x;
    const int og  = tid & 127;
    const int lg  = tid >> 7;                     // wave-uniform
    const int lg_u = __builtin_amdgcn_readfirstlane(lg);

    const float* __restrict__ xb = x + (size_t)b * (T_ * DIN);

    float y0 = 0.f, y1 = 0.f, y2 = 0.f, y3 = 0.f;
    // W[m] = xw[row][A0+m]; y[r] uses W[48 - jj + r], jj in [0,48)
    const int A0 = 4 * og + 144 - 48 * lg;        // in [0, 652], 16B aligned

    for (int dh = 0; dh < 2; ++dh) {
        __syncthreads();   // previous-phase readers done before overwrite
        // stage x[t0-192 .. t0+512) x d in [20dh,20dh+20) -> xw[dl][tt]
        for (int k = 0; k < 7; ++k) {
            const int phi = tid + 512 * k;
            if (phi < TT * 5) {
                const int tr = phi / 5, dq = phi - tr * 5;
                const int tg = t0 - L_ + tr;
                float4 v = make_float4(0.f, 0.f, 0.f, 0.f);
                if (tg >= 0)
                    v = *(const float4*)&xb[tg * DIN + dh * 20 + dq * 4];
                float* col = &xw[(dq * 4) * RS + tr];
                col[0]      = v.x;
                col[RS]     = v.y;
                col[2 * RS] = v.z;
                col[3 * RS] = v.w;
            }
        }
        __syncthreads();

        for (int dl = 0; dl < 20; ++dl) {
            const float* __restrict__ rowp = &xw[dl * RS];
            const float* __restrict__ gr = &d_gT[(dh * 20 + dl) * L_ + 48 * lg_u];
            float W[52];
#pragma unroll
            for (int q = 0; q < 13; ++q)
                *(float4*)&W[4 * q] = *(const float4*)&rowp[A0 + 4 * q];
#pragma unroll
            for (int jj = 0; jj < 48; ++jj) {
                const float gj = gr[jj];          // wave-uniform -> s_load
                y0 = fmaf(gj, W[48 - jj + 0], y0);
                y1 = fmaf(gj, W[48 - jj + 1], y1);
                y2 = fmaf(gj, W[48 - jj + 2], y2);
                y3 = fmaf(gj, W[48 - jj + 3], y3);
            }
        }
    }

    // reduce 4 lag-slice partials per output (lane-contiguous float4s)
    __syncthreads();
    if (lg > 0)
        *(float4*)&xw[((lg - 1) * 128 + og) * 4] = make_float4(y0, y1, y2, y3);
    __syncthreads();
    if (lg == 0) {
#pragma unroll
        for (int pw = 0; pw < 3; ++pw) {
            float4 u = *(const float4*)&xw[(pw * 128 + og) * 4];
            y0 += u.x; y1 += u.y; y2 += u.z; y3 += u.w;
        }
        const float4 c4 = *(const float4*)&d_c[t0 + 4 * og];
        float4 o4;
        o4.x = sigmf(y0 + c4.x); o4.y = sigmf(y1 + c4.y);
        o4.z = sigmf(y2 + c4.z); o4.w = sigmf(y3 + c4.w);
        *(float4*)&out[(size_t)b * T_ + t0 + 4 * og] = o4;
    }
}

extern "C" void kernel_launch(void* const* d_in, const int* in_sizes, int n_in,
                              void* d_out, int out_size, void* d_ws, size_t ws_size,
                              hipStream_t stream)
{
    const float* x      = (const float*)d_in[0];
    const float* W1     = (const float*)d_in[1];
    const float* b1     = (const float*)d_in[2];
    const float* W2     = (const float*)d_in[3];
    const float* b2     = (const float*)d_in[4];
    const float* Wo     = (const float*)d_in[5];
    const float* bo     = (const float*)d_in[6];
    const float* tau_m  = (const float*)d_in[7];
    const float* tau_n1 = (const float*)d_in[8];
    const float* tau_n2 = (const float*)d_in[9];

    hipLaunchKernelGGL(prepA, dim3(800), dim3(256), 0, stream,
                       Wo, tau_m, tau_n1, tau_n2, b1, b2, bo);
    hipLaunchKernelGGL(prepB, dim3(120), dim3(256), 0, stream, W1, W2);
    hipLaunchKernelGGL(fir_main, dim3(512), dim3(512), 0, stream,
                       x, (float*)d_out);
}

// Round 3
// 168.833 us; speedup vs baseline: 1.6815x; 1.5524x over previous
//
#include <hip/hip_runtime.h>
#include <math.h>

// TwoBranchDH_SFNN: B=128, T=2048, H=512, D_IN=40, D_OUT=1
//
// R14 = R13's FIR collapse + two measured fixes:
//  1) LDS window reads: R12/R13 per-instr conflict arithmetic (45 / 22
//     extra cyc at lane-stride 32B / 16B) shows wave64 ds_read_b128 banks
//     by dword-addr mod 32 across all 64 lanes -> quad-strided windows are
//     inherently ~8-way conflicted. New layout: phi(t) = t + (t>>2)
//     (pad dword per quad, row stride 881) -> lane base = 5*og dwords ->
//     2 lanes/bank (free). Window read = 51 scalar f32 LDS loads with
//     immediate offsets (compiler pairs into ds_read2_b32).
//  2) Launch count: ~24us per extra serialized launch (73/120/120 us gap
//     at 1/3/3 launches). prepA+prepB merged into one prepG kernel that
//     computes g directly (no P intermediate) and c(t) exactly.
//
// out[b,t] = sigmoid( sum_{s<192,d} g[s,d]*x[b,t-s,d] + c(t) ), f32 only.

#define B_   128
#define T_   2048
#define DIN  40
#define L_   192
#define TT   704             // 512 + 192 staged t-window
#define RSQ  881             // phi-padded LDS row stride (dwords)

__device__ float d_gT[DIN * L_];     // [d][s]
__device__ float d_c[T_];            // bias transient + bo

__device__ __forceinline__ float sigmf(float v) { return 1.f / (1.f + __expf(-v)); }

// ---------------- prepG: g (blocks 0..39) + c(t) (blocks 40..103) --------
__global__ __launch_bounds__(256) void prepG(
    const float* __restrict__ W1, const float* __restrict__ b1v,
    const float* __restrict__ W2, const float* __restrict__ b2v,
    const float* __restrict__ Wo, const float* __restrict__ bo,
    const float* __restrict__ tau_m, const float* __restrict__ tau_n1,
    const float* __restrict__ tau_n2)
{
    const int blk = blockIdx.x, tid = threadIdx.x;
    if (blk < 40) {
        // g[d][s] = sum_h Wo*(1-a)(1-b)*(a^{s+1}-b^{s+1})/(a-b)*W[h,dm]
        __shared__ float cw[512], laG[512], lbG[512];
        const int d = blk;
        const int dm = (d < 20) ? d : d - 20;
        for (int i = 0; i < 2; ++i) {
            const int h = tid + 256 * i;
            const float a = sigmf(tau_m[h]);
            float bb = sigmf((d < 20) ? tau_n1[h] : tau_n2[h]);
            float diff = a - bb;
            if (fabsf(diff) < 1e-5f) { bb = a - 1e-5f; diff = 1e-5f; }
            const float w = (d < 20) ? W1[h * 20 + dm] : W2[h * 20 + dm];
            cw[h]  = Wo[h] * (1.f - a) * (1.f - bb) * w / diff;
            laG[h] = log2f(a);
            lbG[h] = log2f(bb);
        }
        __syncthreads();
        if (tid < 192) {
            const float fs1 = (float)(tid + 1);
            float acc = 0.f;
            for (int h = 0; h < 512; ++h)
                acc += cw[h] * (exp2f(fs1 * laG[h]) - exp2f(fs1 * lbG[h]));
            d_gT[d * L_ + tid] = acc;
        }
    } else {
        // c(t) = bo + sum_h [cst - A*a^{t+1} + B1*b1^{t+1} + B2*b2^{t+1}]
        // (exact expansion of the R13-verified zero-state bias response)
        __shared__ float As[512], B1s[512], B2s[512], cst[512],
                         laC[512], lb1C[512], lb2C[512];
        __shared__ float red[8][32];
        for (int i = 0; i < 2; ++i) {
            const int h = tid + 256 * i;
            const float a = sigmf(tau_m[h]);
            float b1c = sigmf(tau_n1[h]); float d1 = a - b1c;
            if (fabsf(d1) < 1e-5f) { b1c = a - 1e-5f; d1 = 1e-5f; }
            float b2c = sigmf(tau_n2[h]); float d2 = a - b2c;
            if (fabsf(d2) < 1e-5f) { b2c = a - 1e-5f; d2 = 1e-5f; }
            const float wv = Wo[h], bb1 = b1v[h], bb2 = b2v[h];
            As[h]  = wv * (bb1 * a * (1.f - b1c) / d1 + bb2 * a * (1.f - b2c) / d2);
            B1s[h] = wv * bb1 * b1c * (1.f - a) / d1;
            B2s[h] = wv * bb2 * b2c * (1.f - a) / d2;
            cst[h] = wv * (bb1 + bb2);
            laC[h] = log2f(a); lb1C[h] = log2f(b1c); lb2C[h] = log2f(b2c);
        }
        __syncthreads();
        const int tl = tid & 31;
        const int hc = tid >> 5;              // 8 h-chunks of 64
        const float ft1 = (float)((blk - 40) * 32 + tl + 1);
        float acc = 0.f;
        for (int hh = 0; hh < 64; ++hh) {
            const int h = hc * 64 + hh;
            acc += cst[h] - As[h] * exp2f(ft1 * laC[h])
                 + B1s[h] * exp2f(ft1 * lb1C[h])
                 + B2s[h] * exp2f(ft1 * lb2C[h]);
        }
        red[hc][tl] = acc;
        __syncthreads();
        if (tid < 32) {
            float s = bo[0];
#pragma unroll
            for (int c = 0; c < 8; ++c) s += red[c][tid];
            d_c[(blk - 40) * 32 + tid] = s;
        }
    }
}

// ---------------- main FIR kernel ----------------
// 512 blocks = 128 b x 4 t-tiles(512). 512 thr = 4 lg x 128 og.
// thread: outputs t0+4*og+{0..3}, lags [48*lg, 48*lg+48).
// LDS layout phi(t) = t + (t>>2): lane window base 5*og dwords ->
// 2 lanes/bank, conflict-free scalar/read2 loads.
__global__ __launch_bounds__(512, 4) void fir_main(const float* __restrict__ x,
                                                   float* __restrict__ out)
{
    __shared__ __align__(16) float xw[20 * RSQ];   // 70480 B -> 2 blocks/CU

    const int blk = blockIdx.x;
    const int b   = blk >> 2;
    const int t0  = (blk & 3) << 9;
    const int tid = threadIdx.x;
    const int og  = tid & 127;
    const int lg  = tid >> 7;                     // wave-uniform
    const int lg_u = __builtin_amdgcn_readfirstlane(lg);

    const float* __restrict__ xb = x + (size_t)b * (T_ * DIN);

    float y0 = 0.f, y1 = 0.f, y2 = 0.f, y3 = 0.f;
    const int A0 = 4 * og + 144 - 48 * lg;        // logical window base
    const int AQ = A0 + (A0 >> 2);                // phi(A0), A0 % 4 == 0

    for (int dh = 0; dh < 2; ++dh) {
        __syncthreads();   // previous-phase readers done before overwrite
        // stage x[t0-192 .. t0+512) x d in [20dh,20dh+20) -> xw[dl][phi(tt)]
        for (int k = 0; k < 7; ++k) {
            const int phi = tid + 512 * k;
            if (phi < TT * 5) {
                const int tr = phi / 5, dq = phi - tr * 5;
                const int tg = t0 - L_ + tr;
                float4 v = make_float4(0.f, 0.f, 0.f, 0.f);
                if (tg >= 0)
                    v = *(const float4*)&xb[tg * DIN + dh * 20 + dq * 4];
                const int tph = tr + (tr >> 2);
                float* colp = &xw[(dq * 4) * RSQ + tph];
                colp[0]       = v.x;
                colp[RSQ]     = v.y;
                colp[2 * RSQ] = v.z;
                colp[3 * RSQ] = v.w;
            }
        }
        __syncthreads();

        for (int dl = 0; dl < 20; ++dl) {
            const float* __restrict__ rowp = &xw[dl * RSQ + AQ];
            const float* __restrict__ gr = &d_gT[(dh * 20 + dl) * L_ + 48 * lg_u];
            float W[52];
#pragma unroll
            for (int m = 1; m < 52; ++m)
                W[m] = rowp[m + (m >> 2)];        // imm-offset, conflict-free
#pragma unroll
            for (int jj = 0; jj < 48; ++jj) {
                const float gj = gr[jj];          // wave-uniform -> s_load
                y0 = fmaf(gj, W[48 - jj + 0], y0);
                y1 = fmaf(gj, W[48 - jj + 1], y1);
                y2 = fmaf(gj, W[48 - jj + 2], y2);
                y3 = fmaf(gj, W[48 - jj + 3], y3);
            }
        }
    }

    // reduce 4 lag-slice partials per output
    __syncthreads();
    if (lg > 0)
        *(float4*)&xw[((lg - 1) * 128 + og) * 4] = make_float4(y0, y1, y2, y3);
    __syncthreads();
    if (lg == 0) {
#pragma unroll
        for (int pw = 0; pw < 3; ++pw) {
            float4 u = *(const float4*)&xw[(pw * 128 + og) * 4];
            y0 += u.x; y1 += u.y; y2 += u.z; y3 += u.w;
        }
        const float4 c4 = *(const float4*)&d_c[t0 + 4 * og];
        float4 o4;
        o4.x = sigmf(y0 + c4.x); o4.y = sigmf(y1 + c4.y);
        o4.z = sigmf(y2 + c4.z); o4.w = sigmf(y3 + c4.w);
        *(float4*)&out[(size_t)b * T_ + t0 + 4 * og] = o4;
    }
}

extern "C" void kernel_launch(void* const* d_in, const int* in_sizes, int n_in,
                              void* d_out, int out_size, void* d_ws, size_t ws_size,
                              hipStream_t stream)
{
    const float* x      = (const float*)d_in[0];
    const float* W1     = (const float*)d_in[1];
    const float* b1     = (const float*)d_in[2];
    const float* W2     = (const float*)d_in[3];
    const float* b2     = (const float*)d_in[4];
    const float* Wo     = (const float*)d_in[5];
    const float* bo     = (const float*)d_in[6];
    const float* tau_m  = (const float*)d_in[7];
    const float* tau_n1 = (const float*)d_in[8];
    const float* tau_n2 = (const float*)d_in[9];

    hipLaunchKernelGGL(prepG, dim3(104), dim3(256), 0, stream,
                       W1, b1, W2, b2, Wo, bo, tau_m, tau_n1, tau_n2);
    hipLaunchKernelGGL(fir_main, dim3(512), dim3(512), 0, stream,
                       x, (float*)d_out);
}